// Round 7
// baseline (789.847 us; speedup 1.0000x reference)
//
#include <hip/hip_runtime.h>

#define IN_DIM 512
#define OUT_DIM 32
#define KSTEPS 10
#define ALPHA 0.1f
#define SCB 512      // scan block chunk

typedef __attribute__((ext_vector_type(8))) short short8;   // 8 bf16 (4 VGPRs)
typedef __attribute__((ext_vector_type(4))) float floatx4;  // MFMA acc

// ---------------- degree / norm / chunked-CSR build ----------------

__global__ void k_count(const int* __restrict__ src, const int* __restrict__ dst,
                        int* __restrict__ cnt, int E, int cdiv) {
    int e = blockIdx.x * blockDim.x + threadIdx.x;
    if (e < E) {
        int ch = src[e] / cdiv;
        atomicAdd(&cnt[dst[e] * 4 + ch], 1);
    }
}

__global__ void k_rsqrt(const int* __restrict__ cnt, float* __restrict__ dinv, int N) {
    int i = blockIdx.x * blockDim.x + threadIdx.x;
    if (i < N) {
        int d = cnt[4 * i] + cnt[4 * i + 1] + cnt[4 * i + 2] + cnt[4 * i + 3];
        dinv[i] = rsqrtf((float)d + 1.0f);  // +1 self-loop
    }
}

// ---------------- parallel exclusive scan (3 phases) ----------------

__global__ __launch_bounds__(SCB) void k_bsum(const int* __restrict__ v,
                                              int* __restrict__ bsum, int M) {
    __shared__ int s[SCB];
    int i = blockIdx.x * SCB + threadIdx.x;
    s[threadIdx.x] = (i < M) ? v[i] : 0;
    __syncthreads();
    for (int d = SCB / 2; d > 0; d >>= 1) {
        if (threadIdx.x < d) s[threadIdx.x] += s[threadIdx.x + d];
        __syncthreads();
    }
    if (threadIdx.x == 0) bsum[blockIdx.x] = s[0];
}

__global__ __launch_bounds__(1024) void k_bscan(const int* __restrict__ bsum,
                                                int* __restrict__ bsum_off,
                                                int* __restrict__ total_out, int NB) {
    __shared__ int s[1024];
    int t = threadIdx.x;
    s[t] = (t < NB) ? bsum[t] : 0;
    __syncthreads();
    for (int d = 1; d < 1024; d <<= 1) {
        int v = (t >= d) ? s[t - d] : 0;
        __syncthreads();
        s[t] += v;
        __syncthreads();
    }
    if (t < NB) bsum_off[t] = (t == 0) ? 0 : s[t - 1];
    if (t == 0 && total_out) *total_out = s[1023];
}

__global__ __launch_bounds__(SCB) void k_boff(const int* __restrict__ v,
                                              const int* __restrict__ bsum_off,
                                              int* __restrict__ off, int M) {
    __shared__ int s[SCB];
    int t = threadIdx.x;
    int i = blockIdx.x * SCB + t;
    int myv = (i < M) ? v[i] : 0;
    s[t] = myv;
    __syncthreads();
    for (int d = 1; d < SCB; d <<= 1) {
        int u = (t >= d) ? s[t - d] : 0;
        __syncthreads();
        s[t] += u;
        __syncthreads();
    }
    if (i < M) off[i] = bsum_off[blockIdx.x] + s[t] - myv;  // exclusive
}

__global__ void k_fill(const int* __restrict__ src, const int* __restrict__ dst,
                       const float* __restrict__ dinv, const int* __restrict__ off4,
                       int* __restrict__ cur, float2* __restrict__ csr, int E, int cdiv) {
    int e = blockIdx.x * blockDim.x + threadIdx.x;
    if (e < E) {
        int d = dst[e], s = src[e];
        int key = d * 4 + s / cdiv;
        int pos = off4[key] + atomicAdd(&cur[key], 1);
        csr[pos] = make_float2(dinv[s] * dinv[d], __int_as_float(s));
    }
}

// ---------------- bf16 split helpers ----------------

__device__ inline unsigned bf16_rne(float f) {
    unsigned u = __float_as_uint(f);
    return (u + 0x7FFFu + ((u >> 16) & 1u)) >> 16;
}

// W split precompute: Wh/Wl planes (row-major like W), done ONCE per launch.
__global__ void k_wsplit(const float* __restrict__ W, short* __restrict__ Wh,
                         short* __restrict__ Wl, int M) {
    int i = blockIdx.x * blockDim.x + threadIdx.x;
    if (i < M) {
        float f = W[i];
        unsigned hb = bf16_rne(f);
        float fh = __uint_as_float(hb << 16);
        unsigned lb = bf16_rne(f - fh);
        Wh[i] = (short)hb;
        Wl[i] = (short)lb;
    }
}

__device__ inline void split8(const float* __restrict__ p, short8& hi, short8& lo) {
    float4 v0 = *(const float4*)p;
    float4 v1 = *(const float4*)(p + 4);
    float f[8] = {v0.x, v0.y, v0.z, v0.w, v1.x, v1.y, v1.z, v1.w};
#pragma unroll
    for (int j = 0; j < 8; j++) {
        unsigned hb = bf16_rne(f[j]);
        float fh = __uint_as_float(hb << 16);
        unsigned lb = bf16_rne(f[j] - fh);
        hi[j] = (short)hb;
        lo[j] = (short)lb;
    }
}

// ---------------- dense projection: bf16-split MFMA ----------------
// A-frag (m=lane&15, k=quad*8+j) = 8 contiguous floats of one x row.
// D += Ah*Bh + Al*Bh + Ah*Bl  (fp32 acc, err ~2^-17)

__global__ __launch_bounds__(256) void k_gemm3(const float* __restrict__ x,
                                               const short* __restrict__ Wh,
                                               const short* __restrict__ Wl,
                                               const float* __restrict__ bias,
                                               float* __restrict__ h, int N) {
    int wave = threadIdx.x >> 6;
    int lane = threadIdx.x & 63;
    int m = lane & 15;
    int quad = lane >> 4;
    int nodeBase = blockIdx.x * 64 + wave * 16;

    int nodeA = nodeBase + m; if (nodeA >= N) nodeA = N - 1;  // clamp (loads only)
    const float* xrow  = x  + (size_t)nodeA * IN_DIM + quad * 8;
    const short* w0h = Wh + (size_t)m * IN_DIM + quad * 8;          // outs 0..15
    const short* w0l = Wl + (size_t)m * IN_DIM + quad * 8;
    const short* w1h = Wh + (size_t)(m + 16) * IN_DIM + quad * 8;   // outs 16..31
    const short* w1l = Wl + (size_t)(m + 16) * IN_DIM + quad * 8;

    floatx4 acc0 = {0.f, 0.f, 0.f, 0.f};
    floatx4 acc1 = {0.f, 0.f, 0.f, 0.f};

    for (int kc = 0; kc < IN_DIM / 32; kc++) {
        short8 Ah, Al;
        split8(xrow + kc * 32, Ah, Al);
        short8 B0h = *(const short8*)(w0h + kc * 32);
        short8 B0l = *(const short8*)(w0l + kc * 32);
        short8 B1h = *(const short8*)(w1h + kc * 32);
        short8 B1l = *(const short8*)(w1l + kc * 32);
        acc0 = __builtin_amdgcn_mfma_f32_16x16x32_bf16(Ah, B0h, acc0, 0, 0, 0);
        acc1 = __builtin_amdgcn_mfma_f32_16x16x32_bf16(Ah, B1h, acc1, 0, 0, 0);
        acc0 = __builtin_amdgcn_mfma_f32_16x16x32_bf16(Al, B0h, acc0, 0, 0, 0);
        acc1 = __builtin_amdgcn_mfma_f32_16x16x32_bf16(Al, B1h, acc1, 0, 0, 0);
        acc0 = __builtin_amdgcn_mfma_f32_16x16x32_bf16(Ah, B0l, acc0, 0, 0, 0);
        acc1 = __builtin_amdgcn_mfma_f32_16x16x32_bf16(Ah, B1l, acc1, 0, 0, 0);
    }

    // C/D layout: col = lane&15 (out), row = quad*4 + reg (node)
    float b0 = bias[m], b1 = bias[16 + m];
#pragma unroll
    for (int r = 0; r < 4; r++) {
        int node = nodeBase + quad * 4 + r;
        if (node < N) {
            h[(size_t)node * OUT_DIM + m]      = acc0[r] + b0;
            h[(size_t)node * OUT_DIM + 16 + m] = acc1[r] + b1;
        }
    }
}

// ---------------- propagation: pull, float4/lane, unroll-4 ----------------

__global__ __launch_bounds__(256) void k_pull(const int* __restrict__ off4,
                                              const float2* __restrict__ csr,
                                              const float* __restrict__ zprev,
                                              const float* __restrict__ h,
                                              const float* __restrict__ dinv,
                                              float* __restrict__ znext, int N) {
    int t = blockIdx.x * 256 + threadIdx.x;
    int node = t >> 3;
    int l = (t & 7) * 4;
    if (node >= N) return;
    int beg = off4[node * 4];
    int end = off4[node * 4 + 4];
    float a00 = 0.f, a01 = 0.f, a02 = 0.f, a03 = 0.f;
    float a10 = 0.f, a11 = 0.f, a12 = 0.f, a13 = 0.f;
    float a20 = 0.f, a21 = 0.f, a22 = 0.f, a23 = 0.f;
    float a30 = 0.f, a31 = 0.f, a32 = 0.f, a33 = 0.f;
    int j = beg;
    for (; j + 4 <= end; j += 4) {
        float2 r0 = csr[j];
        float2 r1 = csr[j + 1];
        float2 r2 = csr[j + 2];
        float2 r3 = csr[j + 3];
        float4 z0 = *(const float4*)(zprev + (size_t)__float_as_int(r0.y) * OUT_DIM + l);
        float4 z1 = *(const float4*)(zprev + (size_t)__float_as_int(r1.y) * OUT_DIM + l);
        float4 z2 = *(const float4*)(zprev + (size_t)__float_as_int(r2.y) * OUT_DIM + l);
        float4 z3 = *(const float4*)(zprev + (size_t)__float_as_int(r3.y) * OUT_DIM + l);
        a00 = fmaf(r0.x, z0.x, a00); a01 = fmaf(r0.x, z0.y, a01);
        a02 = fmaf(r0.x, z0.z, a02); a03 = fmaf(r0.x, z0.w, a03);
        a10 = fmaf(r1.x, z1.x, a10); a11 = fmaf(r1.x, z1.y, a11);
        a12 = fmaf(r1.x, z1.z, a12); a13 = fmaf(r1.x, z1.w, a13);
        a20 = fmaf(r2.x, z2.x, a20); a21 = fmaf(r2.x, z2.y, a21);
        a22 = fmaf(r2.x, z2.z, a22); a23 = fmaf(r2.x, z2.w, a23);
        a30 = fmaf(r3.x, z3.x, a30); a31 = fmaf(r3.x, z3.y, a31);
        a32 = fmaf(r3.x, z3.z, a32); a33 = fmaf(r3.x, z3.w, a33);
    }
    for (; j < end; j++) {
        float2 r = csr[j];
        float4 z = *(const float4*)(zprev + (size_t)__float_as_int(r.y) * OUT_DIM + l);
        a00 = fmaf(r.x, z.x, a00); a01 = fmaf(r.x, z.y, a01);
        a02 = fmaf(r.x, z.z, a02); a03 = fmaf(r.x, z.w, a03);
    }
    float d = dinv[node];
    float d2 = d * d;
    float4 zs = *(const float4*)(zprev + (size_t)node * OUT_DIM + l);
    float4 hh = *(const float4*)(h + (size_t)node * OUT_DIM + l);
    float s0 = ((a00 + a10) + (a20 + a30)) + d2 * zs.x;
    float s1 = ((a01 + a11) + (a21 + a31)) + d2 * zs.y;
    float s2 = ((a02 + a12) + (a22 + a32)) + d2 * zs.z;
    float s3 = ((a03 + a13) + (a23 + a33)) + d2 * zs.w;
    float4 res = make_float4(fmaf(1.0f - ALPHA, s0, ALPHA * hh.x),
                             fmaf(1.0f - ALPHA, s1, ALPHA * hh.y),
                             fmaf(1.0f - ALPHA, s2, ALPHA * hh.z),
                             fmaf(1.0f - ALPHA, s3, ALPHA * hh.w));
    *(float4*)(znext + (size_t)node * OUT_DIM + l) = res;
}

extern "C" void kernel_launch(void* const* d_in, const int* in_sizes, int n_in,
                              void* d_out, int out_size, void* d_ws, size_t ws_size,
                              hipStream_t stream) {
    const float* x    = (const float*)d_in[0];
    const float* W    = (const float*)d_in[1];
    const float* bias = (const float*)d_in[2];
    const int*   ei   = (const int*)d_in[3];

    const int N = in_sizes[0] / IN_DIM;   // 100000
    const int E = in_sizes[3] / 2;        // 1600000
    const int* src = ei;
    const int* dst = ei + E;
    const int cdiv = (N + 3) / 4;
    const int M = 4 * N;                  // scan length
    const int NB = (M + SCB - 1) / SCB;   // 782 <= 1024
    const int WM = OUT_DIM * IN_DIM;      // 16384

    // workspace layout
    char* ws = (char*)d_ws;
    size_t o = 0;
    float*  h    = (float*)(ws + o);  o += (size_t)N * OUT_DIM * 4;
    float*  A    = (float*)(ws + o);  o += (size_t)N * OUT_DIM * 4;
    float2* csr  = (float2*)(ws + o); o += (size_t)E * 8;
    float*  dinv = (float*)(ws + o);  o += (size_t)N * 4;
    int*    off4 = (int*)(ws + o);    o += (size_t)(M + 1) * 4;
    int*    cnt  = (int*)(ws + o);    o += (size_t)M * 4;
    int*    cur  = (int*)(ws + o);    o += (size_t)M * 4;
    int*    bsum = (int*)(ws + o);    o += (size_t)NB * 4;
    int*    boff = (int*)(ws + o);    o += (size_t)NB * 4;
    short*  Wh   = (short*)(ws + o);  o += (size_t)WM * 2;
    short*  Wl   = (short*)(ws + o);  o += (size_t)WM * 2;

    const int B = 256;
    int gN = (N + B - 1) / B;
    int gE = (E + B - 1) / B;
    int gP = ((size_t)N * 8 + B - 1) / B;   // pull grid (3125)
    int gG = (N + 63) / 64;                 // gemm grid (1563)
    int gW = (WM + B - 1) / B;

    hipMemsetAsync(cnt, 0, (size_t)2 * M * 4, stream);  // cnt + cur (adjacent)

    // degree + norm + chunked CSR
    k_count<<<gE, B, 0, stream>>>(src, dst, cnt, E, cdiv);
    k_rsqrt<<<gN, B, 0, stream>>>(cnt, dinv, N);
    k_bsum<<<NB, SCB, 0, stream>>>(cnt, bsum, M);
    k_bscan<<<1, 1024, 0, stream>>>(bsum, boff, off4 + M, NB);
    k_boff<<<NB, SCB, 0, stream>>>(cnt, boff, off4, M);
    k_fill<<<gE, B, 0, stream>>>(src, dst, dinv, off4, cur, csr, E, cdiv);

    // W bf16-split (once) + dense projection
    k_wsplit<<<gW, B, 0, stream>>>(W, Wh, Wl, WM);
    k_gemm3<<<gG, B, 0, stream>>>(x, Wh, Wl, bias, h, N);

    // K propagation steps; ping-pong A <-> d_out so step 10 lands in d_out
    const float* zprev = h;
    for (int s = 0; s < KSTEPS; s++) {
        float* znext = (s % 2 == 0) ? A : (float*)d_out;
        k_pull<<<gP, B, 0, stream>>>(off4, csr, zprev, h, dinv, znext, N);
        zprev = znext;
    }
}

// Round 8
// 747.103 us; speedup vs baseline: 1.0572x; 1.0572x over previous
//
#include <hip/hip_runtime.h>

#define IN_DIM 512
#define OUT_DIM 32
#define KSTEPS 10
#define ALPHA 0.1f
#define SCB 512      // scan block chunk

typedef __attribute__((ext_vector_type(8))) short short8;   // 8 bf16 (4 VGPRs)
typedef __attribute__((ext_vector_type(4))) float floatx4;  // MFMA acc
typedef _Float16 half4 __attribute__((ext_vector_type(4))); // 8B packed fp16

// ---------------- degree / norm / chunked-CSR build ----------------

__global__ void k_count(const int* __restrict__ src, const int* __restrict__ dst,
                        int* __restrict__ cnt, int E, int cdiv) {
    int e = blockIdx.x * blockDim.x + threadIdx.x;
    if (e < E) {
        int ch = src[e] / cdiv;
        atomicAdd(&cnt[dst[e] * 4 + ch], 1);
    }
}

__global__ void k_rsqrt(const int* __restrict__ cnt, float* __restrict__ dinv, int N) {
    int i = blockIdx.x * blockDim.x + threadIdx.x;
    if (i < N) {
        int d = cnt[4 * i] + cnt[4 * i + 1] + cnt[4 * i + 2] + cnt[4 * i + 3];
        dinv[i] = rsqrtf((float)d + 1.0f);  // +1 self-loop
    }
}

// ---------------- parallel exclusive scan (3 phases) ----------------

__global__ __launch_bounds__(SCB) void k_bsum(const int* __restrict__ v,
                                              int* __restrict__ bsum, int M) {
    __shared__ int s[SCB];
    int i = blockIdx.x * SCB + threadIdx.x;
    s[threadIdx.x] = (i < M) ? v[i] : 0;
    __syncthreads();
    for (int d = SCB / 2; d > 0; d >>= 1) {
        if (threadIdx.x < d) s[threadIdx.x] += s[threadIdx.x + d];
        __syncthreads();
    }
    if (threadIdx.x == 0) bsum[blockIdx.x] = s[0];
}

__global__ __launch_bounds__(1024) void k_bscan(const int* __restrict__ bsum,
                                                int* __restrict__ bsum_off,
                                                int* __restrict__ total_out, int NB) {
    __shared__ int s[1024];
    int t = threadIdx.x;
    s[t] = (t < NB) ? bsum[t] : 0;
    __syncthreads();
    for (int d = 1; d < 1024; d <<= 1) {
        int v = (t >= d) ? s[t - d] : 0;
        __syncthreads();
        s[t] += v;
        __syncthreads();
    }
    if (t < NB) bsum_off[t] = (t == 0) ? 0 : s[t - 1];
    if (t == 0 && total_out) *total_out = s[1023];
}

__global__ __launch_bounds__(SCB) void k_boff(const int* __restrict__ v,
                                              const int* __restrict__ bsum_off,
                                              int* __restrict__ off, int M) {
    __shared__ int s[SCB];
    int t = threadIdx.x;
    int i = blockIdx.x * SCB + t;
    int myv = (i < M) ? v[i] : 0;
    s[t] = myv;
    __syncthreads();
    for (int d = 1; d < SCB; d <<= 1) {
        int u = (t >= d) ? s[t - d] : 0;
        __syncthreads();
        s[t] += u;
        __syncthreads();
    }
    if (i < M) off[i] = bsum_off[blockIdx.x] + s[t] - myv;  // exclusive
}

__global__ void k_fill(const int* __restrict__ src, const int* __restrict__ dst,
                       const float* __restrict__ dinv, const int* __restrict__ off4,
                       int* __restrict__ cur, float2* __restrict__ csr, int E, int cdiv) {
    int e = blockIdx.x * blockDim.x + threadIdx.x;
    if (e < E) {
        int d = dst[e], s = src[e];
        int key = d * 4 + s / cdiv;
        int pos = off4[key] + atomicAdd(&cur[key], 1);
        csr[pos] = make_float2(dinv[s] * dinv[d], __int_as_float(s));
    }
}

// ---------------- bf16 split helpers ----------------

__device__ inline unsigned bf16_rne(float f) {
    unsigned u = __float_as_uint(f);
    return (u + 0x7FFFu + ((u >> 16) & 1u)) >> 16;
}

__global__ void k_wsplit(const float* __restrict__ W, short* __restrict__ Wh,
                         short* __restrict__ Wl, int M) {
    int i = blockIdx.x * blockDim.x + threadIdx.x;
    if (i < M) {
        float f = W[i];
        unsigned hb = bf16_rne(f);
        float fh = __uint_as_float(hb << 16);
        unsigned lb = bf16_rne(f - fh);
        Wh[i] = (short)hb;
        Wl[i] = (short)lb;
    }
}

__device__ inline void split8(const float* __restrict__ p, short8& hi, short8& lo) {
    float4 v0 = *(const float4*)p;
    float4 v1 = *(const float4*)(p + 4);
    float f[8] = {v0.x, v0.y, v0.z, v0.w, v1.x, v1.y, v1.z, v1.w};
#pragma unroll
    for (int j = 0; j < 8; j++) {
        unsigned hb = bf16_rne(f[j]);
        float fh = __uint_as_float(hb << 16);
        unsigned lb = bf16_rne(f[j] - fh);
        hi[j] = (short)hb;
        lo[j] = (short)lb;
    }
}

// ---------------- dense projection: bf16-split MFMA ----------------
// Writes h (fp32, for the alpha*h term) AND z0 (fp16 seed for propagation).

__global__ __launch_bounds__(256) void k_gemm3(const float* __restrict__ x,
                                               const short* __restrict__ Wh,
                                               const short* __restrict__ Wl,
                                               const float* __restrict__ bias,
                                               float* __restrict__ h,
                                               _Float16* __restrict__ z0, int N) {
    int wave = threadIdx.x >> 6;
    int lane = threadIdx.x & 63;
    int m = lane & 15;
    int quad = lane >> 4;
    int nodeBase = blockIdx.x * 64 + wave * 16;

    int nodeA = nodeBase + m; if (nodeA >= N) nodeA = N - 1;  // clamp (loads only)
    const float* xrow  = x  + (size_t)nodeA * IN_DIM + quad * 8;
    const short* w0h = Wh + (size_t)m * IN_DIM + quad * 8;          // outs 0..15
    const short* w0l = Wl + (size_t)m * IN_DIM + quad * 8;
    const short* w1h = Wh + (size_t)(m + 16) * IN_DIM + quad * 8;   // outs 16..31
    const short* w1l = Wl + (size_t)(m + 16) * IN_DIM + quad * 8;

    floatx4 acc0 = {0.f, 0.f, 0.f, 0.f};
    floatx4 acc1 = {0.f, 0.f, 0.f, 0.f};

    for (int kc = 0; kc < IN_DIM / 32; kc++) {
        short8 Ah, Al;
        split8(xrow + kc * 32, Ah, Al);
        short8 B0h = *(const short8*)(w0h + kc * 32);
        short8 B0l = *(const short8*)(w0l + kc * 32);
        short8 B1h = *(const short8*)(w1h + kc * 32);
        short8 B1l = *(const short8*)(w1l + kc * 32);
        acc0 = __builtin_amdgcn_mfma_f32_16x16x32_bf16(Ah, B0h, acc0, 0, 0, 0);
        acc1 = __builtin_amdgcn_mfma_f32_16x16x32_bf16(Ah, B1h, acc1, 0, 0, 0);
        acc0 = __builtin_amdgcn_mfma_f32_16x16x32_bf16(Al, B0h, acc0, 0, 0, 0);
        acc1 = __builtin_amdgcn_mfma_f32_16x16x32_bf16(Al, B1h, acc1, 0, 0, 0);
        acc0 = __builtin_amdgcn_mfma_f32_16x16x32_bf16(Ah, B0l, acc0, 0, 0, 0);
        acc1 = __builtin_amdgcn_mfma_f32_16x16x32_bf16(Ah, B1l, acc1, 0, 0, 0);
    }

    // C/D layout: col = lane&15 (out), row = quad*4 + reg (node)
    float b0 = bias[m], b1 = bias[16 + m];
#pragma unroll
    for (int r = 0; r < 4; r++) {
        int node = nodeBase + quad * 4 + r;
        if (node < N) {
            float v0 = acc0[r] + b0;
            float v1 = acc1[r] + b1;
            h[(size_t)node * OUT_DIM + m]       = v0;
            h[(size_t)node * OUT_DIM + 16 + m]  = v1;
            z0[(size_t)node * OUT_DIM + m]      = (_Float16)v0;
            z0[(size_t)node * OUT_DIM + 16 + m] = (_Float16)v1;
        }
    }
}

// ---------------- propagation: pull, fp16 z, half4/lane ----------------
// 8 lanes per dst node; lane owns 4 channels (8B fp16). z is 6.4MB ->
// src-chunk windows 1.6MB, L2-resident. Last step writes fp32 to d_out
// (no fp16 rounding on the final output).

__global__ __launch_bounds__(256) void k_pull(const int* __restrict__ off4,
                                              const float2* __restrict__ csr,
                                              const _Float16* __restrict__ zprev,
                                              const float* __restrict__ h,
                                              const float* __restrict__ dinv,
                                              _Float16* __restrict__ znext,
                                              float* __restrict__ outF, int N) {
    int t = blockIdx.x * 256 + threadIdx.x;
    int node = t >> 3;
    int l = (t & 7) * 4;
    if (node >= N) return;
    int beg = off4[node * 4];
    int end = off4[node * 4 + 4];
    float a00 = 0.f, a01 = 0.f, a02 = 0.f, a03 = 0.f;
    float a10 = 0.f, a11 = 0.f, a12 = 0.f, a13 = 0.f;
    int j = beg;
    for (; j + 2 <= end; j += 2) {
        float2 r0 = csr[j];
        float2 r1 = csr[j + 1];
        half4 z0 = *(const half4*)(zprev + (size_t)__float_as_int(r0.y) * OUT_DIM + l);
        half4 z1 = *(const half4*)(zprev + (size_t)__float_as_int(r1.y) * OUT_DIM + l);
        a00 = fmaf(r0.x, (float)z0[0], a00); a01 = fmaf(r0.x, (float)z0[1], a01);
        a02 = fmaf(r0.x, (float)z0[2], a02); a03 = fmaf(r0.x, (float)z0[3], a03);
        a10 = fmaf(r1.x, (float)z1[0], a10); a11 = fmaf(r1.x, (float)z1[1], a11);
        a12 = fmaf(r1.x, (float)z1[2], a12); a13 = fmaf(r1.x, (float)z1[3], a13);
    }
    if (j < end) {
        float2 r = csr[j];
        half4 z = *(const half4*)(zprev + (size_t)__float_as_int(r.y) * OUT_DIM + l);
        a00 = fmaf(r.x, (float)z[0], a00); a01 = fmaf(r.x, (float)z[1], a01);
        a02 = fmaf(r.x, (float)z[2], a02); a03 = fmaf(r.x, (float)z[3], a03);
    }
    float d = dinv[node];
    float d2 = d * d;
    half4 zs = *(const half4*)(zprev + (size_t)node * OUT_DIM + l);
    float4 hh = *(const float4*)(h + (size_t)node * OUT_DIM + l);
    float s0 = (a00 + a10) + d2 * (float)zs[0];
    float s1 = (a01 + a11) + d2 * (float)zs[1];
    float s2 = (a02 + a12) + d2 * (float)zs[2];
    float s3 = (a03 + a13) + d2 * (float)zs[3];
    float r0 = fmaf(1.0f - ALPHA, s0, ALPHA * hh.x);
    float r1 = fmaf(1.0f - ALPHA, s1, ALPHA * hh.y);
    float r2 = fmaf(1.0f - ALPHA, s2, ALPHA * hh.z);
    float r3 = fmaf(1.0f - ALPHA, s3, ALPHA * hh.w);
    if (outF) {
        *(float4*)(outF + (size_t)node * OUT_DIM + l) = make_float4(r0, r1, r2, r3);
    } else {
        half4 o;
        o[0] = (_Float16)r0; o[1] = (_Float16)r1;
        o[2] = (_Float16)r2; o[3] = (_Float16)r3;
        *(half4*)(znext + (size_t)node * OUT_DIM + l) = o;
    }
}

extern "C" void kernel_launch(void* const* d_in, const int* in_sizes, int n_in,
                              void* d_out, int out_size, void* d_ws, size_t ws_size,
                              hipStream_t stream) {
    const float* x    = (const float*)d_in[0];
    const float* W    = (const float*)d_in[1];
    const float* bias = (const float*)d_in[2];
    const int*   ei   = (const int*)d_in[3];

    const int N = in_sizes[0] / IN_DIM;   // 100000
    const int E = in_sizes[3] / 2;        // 1600000
    const int* src = ei;
    const int* dst = ei + E;
    const int cdiv = (N + 3) / 4;
    const int M = 4 * N;                  // scan length
    const int NB = (M + SCB - 1) / SCB;   // 782 <= 1024
    const int WM = OUT_DIM * IN_DIM;      // 16384

    // workspace layout
    char* ws = (char*)d_ws;
    size_t o = 0;
    float*     h    = (float*)(ws + o);     o += (size_t)N * OUT_DIM * 4;  // 12.8 MB
    _Float16*  zA   = (_Float16*)(ws + o);  o += (size_t)N * OUT_DIM * 2;  // 6.4 MB
    _Float16*  zB   = (_Float16*)(ws + o);  o += (size_t)N * OUT_DIM * 2;  // 6.4 MB
    float2*    csr  = (float2*)(ws + o);    o += (size_t)E * 8;            // 12.8 MB
    float*     dinv = (float*)(ws + o);     o += (size_t)N * 4;
    int*       off4 = (int*)(ws + o);       o += (size_t)(M + 1) * 4;
    int*       cnt  = (int*)(ws + o);       o += (size_t)M * 4;
    int*       cur  = (int*)(ws + o);       o += (size_t)M * 4;
    int*       bsum = (int*)(ws + o);       o += (size_t)NB * 4;
    int*       boff = (int*)(ws + o);       o += (size_t)NB * 4;
    short*     Wh   = (short*)(ws + o);     o += (size_t)WM * 2;
    short*     Wl   = (short*)(ws + o);     o += (size_t)WM * 2;

    const int B = 256;
    int gN = (N + B - 1) / B;
    int gE = (E + B - 1) / B;
    int gP = ((size_t)N * 8 + B - 1) / B;   // pull grid (3125)
    int gG = (N + 63) / 64;                 // gemm grid (1563)
    int gW = (WM + B - 1) / B;

    hipMemsetAsync(cnt, 0, (size_t)2 * M * 4, stream);  // cnt + cur (adjacent)

    // degree + norm + chunked CSR
    k_count<<<gE, B, 0, stream>>>(src, dst, cnt, E, cdiv);
    k_rsqrt<<<gN, B, 0, stream>>>(cnt, dinv, N);
    k_bsum<<<NB, SCB, 0, stream>>>(cnt, bsum, M);
    k_bscan<<<1, 1024, 0, stream>>>(bsum, boff, off4 + M, NB);
    k_boff<<<NB, SCB, 0, stream>>>(cnt, boff, off4, M);
    k_fill<<<gE, B, 0, stream>>>(src, dst, dinv, off4, cur, csr, E, cdiv);

    // W bf16-split (once) + dense projection (h fp32 + z0 fp16 seed)
    k_wsplit<<<gW, B, 0, stream>>>(W, Wh, Wl, WM);
    k_gemm3<<<gG, B, 0, stream>>>(x, Wh, Wl, bias, h, zA, N);

    // K propagation steps in fp16; final step writes fp32 directly to d_out
    for (int s = 0; s < KSTEPS; s++) {
        const _Float16* zprev = (s % 2 == 0) ? zA : zB;
        _Float16* znext = (s % 2 == 0) ? zB : zA;
        float* outF = (s == KSTEPS - 1) ? (float*)d_out : nullptr;
        k_pull<<<gP, B, 0, stream>>>(off4, csr, zprev, h, dinv, znext, outF, N);
    }
}